// Round 1
// baseline (7586.717 us; speedup 1.0000x reference)
//
#include <hip/hip_runtime.h>
#include <cstdint>
#include <cstddef>

// FoldingBlock: p1 = up(p); p2 = down(p1); out = p1 + up(p - p2)
// up(): tile p (B,64,512)->(B,256,512), concat pts(256,2) -> Linear+ReLU (514->512)
//       pcat = [ptile, up_out] (B,256,1024)
//       h = relu(pcat@Wh+bh) (256), l = relu(pcat@Wl+bl) (256), g = relu(pcat@Wg+bg) (1024)
//       attn = softmax(l @ h^T); x = pcat + attn@g
//       out = relu(relu(x@Wf1+bf1)@Wf2+bf2) (B,256,256)
// down(): reshape (B,256,256)->(B,64,1024); relu(@W_down+b_down) -> (B,64,512)
//
// Round 1: fp32 correctness baseline. One templated 64x64x16 LDS-tiled GEMM,
// 4x4 micro-tile per thread, all concats/adds fused into loads/epilogues.

#define BM 64
#define BN 64
#define BK 16

// Modes:
// 0 UP:   out = relu(ptile@W_up[0:512] + pts@W_up[512:514] + b)    A0=p(in), W=W_up
// 1 CAT:  out = relu(cat(p,upout)@W + b)                            A0=p, A1=upout
// 2 MM:   out = l @ h^T (per-batch NT)                              A0=l, W=h
// 3 X:    out = attn @ g + cat(p,upout)                             A0=attn, W=g(per-batch), EX0=p, EX1=upout
// 4 RELU: out = relu(A@W + b)                                       A0=x
// 5 F2:   out = relu(A@W + b) (+ EX0 if non-null)                   A0=f1out, EX0=p1
// 6 DOWN: out = EX0 - relu(reshape(A)@W + b)  (p_delta)             A0=p1, EX0=p

template<int MODE>
__global__ __launch_bounds__(256)
void gemm_k(const float* __restrict__ A0, const float* __restrict__ A1,
            const float* __restrict__ W,  const float* __restrict__ bias,
            const float* __restrict__ EX0, const float* __restrict__ EX1,
            float* __restrict__ out, int M, int N, int K)
{
    __shared__ float As[BK][BM + 1];
    __shared__ float Bs[BK][BN + 1];

    const int b   = blockIdx.z;
    const int tid = threadIdx.x;
    const int tx  = tid & 15;       // 16 cols of threads
    const int ty  = tid >> 4;       // 16 rows of threads
    const int gm0 = blockIdx.y * BM;
    const int gn0 = blockIdx.x * BN;

    float acc[4][4] = {};

    for (int k0 = 0; k0 < K; k0 += BK) {
        // ---- load A tile (BM x BK = 1024 elems, 4 per thread) ----
        #pragma unroll
        for (int t = 0; t < 4; ++t) {
            int idx = tid + t * 256;
            int m  = idx >> 4;
            int kk = idx & 15;
            int gm = gm0 + m;
            int gk = k0 + kk;
            float v;
            if constexpr (MODE == 0) {
                v = A0[((size_t)b * 64 + (gm & 63)) * 512 + gk];
            } else if constexpr (MODE == 1) {
                if (gk < 512) v = A0[((size_t)b * 64 + (gm & 63)) * 512 + gk];
                else          v = A1[((size_t)b * 256 + gm) * 512 + (gk - 512)];
            } else if constexpr (MODE == 6) {
                // reshape (256,256)->(64,1024): A[i,c] = p1[i*4 + c/256, c%256]
                v = A0[((size_t)b * 256 + gm * 4 + (gk >> 8)) * 256 + (gk & 255)];
            } else {
                v = A0[((size_t)b * M + gm) * K + gk];
            }
            As[kk][m] = v;
        }
        // ---- load B tile (BK x BN = 1024 elems, 4 per thread) ----
        #pragma unroll
        for (int t = 0; t < 4; ++t) {
            int idx = tid + t * 256;
            float v;
            int kk, n;
            if constexpr (MODE == 2) {
                // B[k][n] = h[n, k]  (per-batch, NT)
                n  = idx >> 4;
                kk = idx & 15;
                v = W[((size_t)b * N + gn0 + n) * K + (k0 + kk)];
            } else {
                kk = idx >> 6;
                n  = idx & 63;
                const float* Bp = (MODE == 3) ? (W + (size_t)b * K * N) : W;
                v = Bp[(size_t)(k0 + kk) * N + gn0 + n];
            }
            Bs[kk][n] = v;
        }
        __syncthreads();

        #pragma unroll
        for (int kk = 0; kk < BK; ++kk) {
            float a[4], bb[4];
            #pragma unroll
            for (int i = 0; i < 4; ++i) a[i] = As[kk][ty * 4 + i];
            #pragma unroll
            for (int j = 0; j < 4; ++j) bb[j] = Bs[kk][tx * 4 + j];
            #pragma unroll
            for (int i = 0; i < 4; ++i)
                #pragma unroll
                for (int j = 0; j < 4; ++j)
                    acc[i][j] += a[i] * bb[j];
        }
        __syncthreads();
    }

    // ---- epilogue ----
    #pragma unroll
    for (int i = 0; i < 4; ++i) {
        int gm = gm0 + ty * 4 + i;
        #pragma unroll
        for (int j = 0; j < 4; ++j) {
            int gn = gn0 + tx * 4 + j;
            float v = acc[i][j];
            if constexpr (MODE == 0) {
                // pts columns (rank-2 update): pts[r] = (-0.3+0.04*(r>>4), -0.3+0.04*(r&15))
                float px = -0.3f + 0.04f * (float)(gm >> 4);
                float py = -0.3f + 0.04f * (float)(gm & 15);
                v += px * W[(size_t)512 * N + gn] + py * W[(size_t)513 * N + gn];
                v = fmaxf(v + bias[gn], 0.0f);
            } else if constexpr (MODE == 1 || MODE == 4) {
                v = fmaxf(v + bias[gn], 0.0f);
            } else if constexpr (MODE == 3) {
                float c = (gn < 512) ? EX0[((size_t)b * 64 + (gm & 63)) * 512 + gn]
                                     : EX1[((size_t)b * 256 + gm) * 512 + (gn - 512)];
                v += c;
            } else if constexpr (MODE == 5) {
                v = fmaxf(v + bias[gn], 0.0f);
                if (EX0) v += EX0[((size_t)b * M + gm) * N + gn];
            } else if constexpr (MODE == 6) {
                v = fmaxf(v + bias[gn], 0.0f);
                v = EX0[((size_t)b * M + gm) * N + gn] - v;   // p - down(p1)
            }
            out[((size_t)b * M + gm) * N + gn] = v;
        }
    }
}

// One wave per row of 256 floats; in-place softmax.
__global__ __launch_bounds__(64)
void softmax_k(float* __restrict__ attn)
{
    const size_t row = blockIdx.x;
    float* r = attn + row * 256;
    const int lane = threadIdx.x;
    float4 v = reinterpret_cast<float4*>(r)[lane];
    float mx = fmaxf(fmaxf(v.x, v.y), fmaxf(v.z, v.w));
    #pragma unroll
    for (int o = 32; o > 0; o >>= 1) mx = fmaxf(mx, __shfl_xor(mx, o));
    float e0 = expf(v.x - mx), e1 = expf(v.y - mx), e2 = expf(v.z - mx), e3 = expf(v.w - mx);
    float s = e0 + e1 + e2 + e3;
    #pragma unroll
    for (int o = 32; o > 0; o >>= 1) s += __shfl_xor(s, o);
    float inv = 1.0f / s;
    reinterpret_cast<float4*>(r)[lane] = make_float4(e0 * inv, e1 * inv, e2 * inv, e3 * inv);
}

extern "C" void kernel_launch(void* const* d_in, const int* in_sizes, int n_in,
                              void* d_out, int out_size, void* d_ws, size_t ws_size,
                              hipStream_t stream)
{
    const float* p      = (const float*)d_in[0];
    const float* W_up   = (const float*)d_in[1];
    const float* b_up   = (const float*)d_in[2];
    const float* Wh     = (const float*)d_in[3];
    const float* bh     = (const float*)d_in[4];
    const float* Wl     = (const float*)d_in[5];
    const float* bl     = (const float*)d_in[6];
    const float* Wg     = (const float*)d_in[7];
    const float* bg     = (const float*)d_in[8];
    const float* Wf1    = (const float*)d_in[9];
    const float* bf1    = (const float*)d_in[10];
    const float* Wf2    = (const float*)d_in[11];
    const float* bf2    = (const float*)d_in[12];
    const float* W_down = (const float*)d_in[13];
    const float* b_down = (const float*)d_in[14];
    // d_in[15]=m, d_in[16]=n : fixed 16x16 grid (pts closed-form in kernel)

    const int B = in_sizes[0] / (64 * 512);
    float* out = (float*)d_out;

    // per-batch workspace floats
    const size_t F_UP = 256 * 512, F_H = 256 * 256, F_L = 256 * 256, F_G = (size_t)256 * 1024;
    const size_t F_AT = 256 * 256, F_X = (size_t)256 * 1024, F_P1 = 256 * 256, F_PD = 64 * 512;
    const size_t perB = F_UP + F_H + F_L + F_G + F_AT + F_X + F_P1 + F_PD;  // 950272 floats

    int BC = B;
    while (BC > 1 && (size_t)BC * perB * sizeof(float) > ws_size) BC >>= 1;

    float* wsf    = (float*)d_ws;
    float* upout  = wsf;
    float* hbuf   = upout + (size_t)BC * F_UP;
    float* lbuf   = hbuf  + (size_t)BC * F_H;
    float* gbuf   = lbuf  + (size_t)BC * F_L;
    float* attn   = gbuf  + (size_t)BC * F_G;
    float* xbuf   = attn  + (size_t)BC * F_AT;
    float* p1     = xbuf  + (size_t)BC * F_X;
    float* pdelta = p1    + (size_t)BC * F_P1;

    dim3 blk(256);

    auto run_up = [&](const float* pin, float* outp, const float* addsrc, int bc) {
        // up-proj (K=512 loop + pts rank-2 epilogue): (bc,256,512)
        gemm_k<0><<<dim3(8, 4, bc), blk, 0, stream>>>(pin, nullptr, W_up, b_up, nullptr, nullptr, upout, 256, 512, 512);
        // h, l, g from cat(ptile, upout) (K=1024)
        gemm_k<1><<<dim3(4, 4, bc), blk, 0, stream>>>(pin, upout, Wh, bh, nullptr, nullptr, hbuf, 256, 256, 1024);
        gemm_k<1><<<dim3(4, 4, bc), blk, 0, stream>>>(pin, upout, Wl, bl, nullptr, nullptr, lbuf, 256, 256, 1024);
        gemm_k<1><<<dim3(16, 4, bc), blk, 0, stream>>>(pin, upout, Wg, bg, nullptr, nullptr, gbuf, 256, 1024, 1024);
        // attn logits = l @ h^T
        gemm_k<2><<<dim3(4, 4, bc), blk, 0, stream>>>(lbuf, nullptr, hbuf, nullptr, nullptr, nullptr, attn, 256, 256, 256);
        softmax_k<<<dim3(bc * 256), dim3(64), 0, stream>>>(attn);
        // x = attn @ g + cat(ptile, upout)
        gemm_k<3><<<dim3(16, 4, bc), blk, 0, stream>>>(attn, nullptr, gbuf, nullptr, pin, upout, xbuf, 256, 1024, 256);
        // f1 (reuse upout as f1out: upout dead after x)
        gemm_k<4><<<dim3(8, 4, bc), blk, 0, stream>>>(xbuf, nullptr, Wf1, bf1, nullptr, nullptr, upout, 256, 512, 1024);
        // f2 (+ optional residual add)
        gemm_k<5><<<dim3(4, 4, bc), blk, 0, stream>>>(upout, nullptr, Wf2, bf2, addsrc, nullptr, outp, 256, 256, 512);
    };

    for (int b0 = 0; b0 < B; b0 += BC) {
        int bc = (B - b0 < BC) ? (B - b0) : BC;
        const float* pin = p + (size_t)b0 * 64 * 512;
        // up #1 -> p1
        run_up(pin, p1, nullptr, bc);
        // p_delta = p - down(p1)
        gemm_k<6><<<dim3(8, 1, bc), blk, 0, stream>>>(p1, nullptr, W_down, b_down, pin, nullptr, pdelta, 64, 512, 1024);
        // up #2 (input p_delta) -> d_out chunk, fused "+ p1"
        run_up(pdelta, out + (size_t)b0 * 256 * 256, p1, bc);
    }
}

// Round 2
// 1187.644 us; speedup vs baseline: 6.3880x; 6.3880x over previous
//
#include <hip/hip_runtime.h>
#include <cstdint>
#include <cstddef>

// FoldingBlock bf16-MFMA implementation (round 2).
// p1 = up(p); pdelta = p - down(p1); out = p1 + up(pdelta)
// All GEMMs: v_mfma_f32_16x16x32_bf16, 128x128 tile, BK=32, 4 waves (2x2),
// single-buffer LDS staged via global_load_lds width=16 (m97 structure).
// B operands pre-transposed to [N][K] so A- and B-fragments read identically.

typedef unsigned short u16;
typedef __bf16 bf16x8 __attribute__((ext_vector_type(8)));
typedef float f32x4 __attribute__((ext_vector_type(4)));

__device__ __forceinline__ u16 f2bf(float f) {
    unsigned u = __builtin_bit_cast(unsigned, f);
    unsigned r = (u + 0x7fffu + ((u >> 16) & 1u)) >> 16;
    return (u16)r;
}
__device__ __forceinline__ float bf2f(u16 h) {
    unsigned u = ((unsigned)h) << 16;
    return __builtin_bit_cast(float, u);
}
__device__ __forceinline__ bf16x8 ldfrag(const u16* p) {
    return __builtin_bit_cast(bf16x8, *reinterpret_cast<const uint4*>(p));
}
__device__ __forceinline__ void gload16(const u16* g, u16* l) {
    __builtin_amdgcn_global_load_lds((__attribute__((address_space(1))) void*)g,
                                     (__attribute__((address_space(3))) void*)l,
                                     16, 0, 0);
}

// Modes:
// 0 UP:   A=p_bf (rows tiled &63, K=512), B=W_upT; epi: pts rank-2 (fp32 W_up) + bias + relu -> bf16
// 1 CAT:  A=cat(p_bf tiled, upout) K=1024, B=W{h,l,g}T; epi: bias+relu -> bf16
// 2 MM:   A=l, B=h (per-batch NT); epi: none -> fp32 logits
// 3 X:    A=attn_bf, B=gT (per-batch); epi: += cat(p fp32, upout bf16) -> bf16
// 4 F1:   A=x, B=Wf1T; epi: bias+relu -> bf16
// 5 F2:   A=f1, B=Wf2T; epi: bias+relu (+EXf fp32 if set) -> fp32 (+opt bf16)
// 6 DOWN: A=reshape(p1_bf) [64][1024], B=W_downT; epi: pdelta = p(fp32) - relu(.+bias) -> fp32+bf16
template<int MODE>
__global__ __launch_bounds__(256)
void mgemm(const u16* __restrict__ A0, const u16* __restrict__ A1,
           const u16* __restrict__ Bt, const float* __restrict__ bias,
           const u16* __restrict__ EXb1, const float* __restrict__ EXf,
           float* __restrict__ outF, u16* __restrict__ outB,
           float* __restrict__ outF2,
           int M, int N, int K, long sB)
{
    __shared__ __align__(16) u16 As[128 * 32];
    __shared__ __align__(16) u16 Bs[128 * 32];

    const int b    = blockIdx.z;
    const int tid  = threadIdx.x;
    const int lane = tid & 63;
    const int w    = tid >> 6;
    const int wr   = w >> 1, wc = w & 1;
    const int gm0  = blockIdx.y * 128, gn0 = blockIdx.x * 128;
    const int lm   = lane & 15, hk = lane >> 4;
    const int rsub = lane >> 2;          // 0..15 (row within 16-row stripe)
    const int ksub = (lane & 3) * 8;     // k element offset 0/8/16/24

    f32x4 acc[4][4];
    #pragma unroll
    for (int i = 0; i < 4; ++i)
        #pragma unroll
        for (int j = 0; j < 4; ++j)
            acc[i][j] = (f32x4){0.f, 0.f, 0.f, 0.f};

    for (int k0 = 0; k0 < K; k0 += 32) {
        #pragma unroll
        for (int c = 0; c < 2; ++c) {
            const int rloc = w * 32 + c * 16 + rsub;
            const int k    = k0 + ksub;
            // ---- A source address (per-lane) ----
            const u16* ga;
            if constexpr (MODE == 0) {
                ga = A0 + (size_t)b * 32768 + (size_t)((gm0 + rloc) & 63) * 512 + k;
            } else if constexpr (MODE == 1) {
                const int gr = gm0 + rloc;
                ga = (k < 512) ? (A0 + (size_t)b * 32768 + (size_t)(gr & 63) * 512 + k)
                               : (A1 + (size_t)b * 131072 + (size_t)gr * 512 + (k - 512));
            } else if constexpr (MODE == 6) {
                int gr = gm0 + rloc; if (gr > 63) gr = 63;
                ga = A0 + (size_t)b * 65536 + (size_t)(gr * 4 + (k >> 8)) * 256 + (k & 255);
            } else {
                ga = A0 + (size_t)b * (size_t)M * K + (size_t)(gm0 + rloc) * K + k;
            }
            gload16(ga, &As[(w * 32 + c * 16) * 32]);
            // ---- B source: BT row-major [N][K] ----
            const u16* gb = Bt + (size_t)b * sB + (size_t)(gn0 + rloc) * K + k;
            gload16(gb, &Bs[(w * 32 + c * 16) * 32]);
        }
        __syncthreads();

        bf16x8 af[4], bfr[4];
        #pragma unroll
        for (int i = 0; i < 4; ++i)
            af[i] = ldfrag(&As[(wr * 64 + i * 16 + lm) * 32 + hk * 8]);
        #pragma unroll
        for (int j = 0; j < 4; ++j)
            bfr[j] = ldfrag(&Bs[(wc * 64 + j * 16 + lm) * 32 + hk * 8]);
        #pragma unroll
        for (int i = 0; i < 4; ++i)
            #pragma unroll
            for (int j = 0; j < 4; ++j)
                acc[i][j] = __builtin_amdgcn_mfma_f32_16x16x32_bf16(af[i], bfr[j], acc[i][j], 0, 0, 0);
        __syncthreads();
    }

    // ---- epilogue ----
    #pragma unroll
    for (int i = 0; i < 4; ++i) {
        #pragma unroll
        for (int r = 0; r < 4; ++r) {
            const int row = gm0 + wr * 64 + i * 16 + hk * 4 + r;
            if (MODE == 6 && row >= M) continue;
            #pragma unroll
            for (int j = 0; j < 4; ++j) {
                const int col = gn0 + wc * 64 + j * 16 + lm;
                float v = acc[i][j][r];
                const size_t oidx = (size_t)b * (size_t)M * N + (size_t)row * N + col;
                if constexpr (MODE == 0) {
                    const float px = -0.3f + 0.04f * (float)(row >> 4);
                    const float py = -0.3f + 0.04f * (float)(row & 15);
                    v += px * EXf[(size_t)512 * 512 + col] + py * EXf[(size_t)513 * 512 + col];
                    v = fmaxf(v + bias[col], 0.0f);
                    outB[oidx] = f2bf(v);
                } else if constexpr (MODE == 1 || MODE == 4) {
                    v = fmaxf(v + bias[col], 0.0f);
                    outB[oidx] = f2bf(v);
                } else if constexpr (MODE == 2) {
                    outF[oidx] = v;
                } else if constexpr (MODE == 3) {
                    float cv = (col < 512)
                        ? EXf[(size_t)b * 32768 + (size_t)(row & 63) * 512 + col]
                        : bf2f(EXb1[(size_t)b * 131072 + (size_t)row * 512 + (col - 512)]);
                    v += cv;
                    outB[oidx] = f2bf(v);
                } else if constexpr (MODE == 5) {
                    v = fmaxf(v + bias[col], 0.0f);
                    if (EXf) v += EXf[oidx];
                    outF[oidx] = v;
                    if (outB) outB[oidx] = f2bf(v);
                } else if constexpr (MODE == 6) {
                    v = fmaxf(v + bias[col], 0.0f);
                    v = EXf[oidx] - v;            // p - down(p1)
                    outF2[oidx] = v;              // pdelta fp32
                    outB[oidx]  = f2bf(v);        // pdelta bf16
                }
            }
        }
    }
}

// Transpose + convert: in [R][C] (fp32 or bf16) -> out [C][R] bf16. R,C multiples of 64.
template<bool F32IN>
__global__ __launch_bounds__(256)
void transpose_k(const void* __restrict__ in_, u16* __restrict__ out, int R, int C)
{
    __shared__ float t[64][65];
    const size_t zo = (size_t)blockIdx.z * (size_t)R * C;
    const int c0 = blockIdx.x * 64, r0 = blockIdx.y * 64;
    const int x = threadIdx.x, y = threadIdx.y;
    #pragma unroll
    for (int i = 0; i < 16; ++i) {
        const int r = y * 16 + i;
        float v;
        if constexpr (F32IN) v = ((const float*)in_)[zo + (size_t)(r0 + r) * C + c0 + x];
        else                 v = bf2f(((const u16*)in_)[zo + (size_t)(r0 + r) * C + c0 + x]);
        t[r][x] = v;
    }
    __syncthreads();
    #pragma unroll
    for (int i = 0; i < 16; ++i) {
        const int c = y * 16 + i;
        out[zo + (size_t)(c0 + c) * R + r0 + x] = f2bf(t[x][c]);
    }
}

__global__ __launch_bounds__(256)
void cvt_k(const float* __restrict__ in, u16* __restrict__ out, int n4)
{
    int i = blockIdx.x * 256 + threadIdx.x;
    const int stride = gridDim.x * 256;
    for (; i < n4; i += stride) {
        float4 v = ((const float4*)in)[i];
        ushort4 o;
        o.x = f2bf(v.x); o.y = f2bf(v.y); o.z = f2bf(v.z); o.w = f2bf(v.w);
        ((ushort4*)out)[i] = o;
    }
}

// One wave per 256-float row: softmax fp32 -> bf16
__global__ __launch_bounds__(64)
void softmax_k(const float* __restrict__ logits, u16* __restrict__ attn)
{
    const size_t row = blockIdx.x;
    const float4 v = ((const float4*)(logits + row * 256))[threadIdx.x];
    float mx = fmaxf(fmaxf(v.x, v.y), fmaxf(v.z, v.w));
    #pragma unroll
    for (int o = 32; o > 0; o >>= 1) mx = fmaxf(mx, __shfl_xor(mx, o));
    float e0 = expf(v.x - mx), e1 = expf(v.y - mx), e2 = expf(v.z - mx), e3 = expf(v.w - mx);
    float s = e0 + e1 + e2 + e3;
    #pragma unroll
    for (int o = 32; o > 0; o >>= 1) s += __shfl_xor(s, o);
    const float inv = 1.0f / s;
    ushort4 o;
    o.x = f2bf(e0 * inv); o.y = f2bf(e1 * inv); o.z = f2bf(e2 * inv); o.w = f2bf(e3 * inv);
    ((ushort4*)(attn + row * 256))[threadIdx.x] = o;
}

extern "C" void kernel_launch(void* const* d_in, const int* in_sizes, int n_in,
                              void* d_out, int out_size, void* d_ws, size_t ws_size,
                              hipStream_t stream)
{
    const float* p      = (const float*)d_in[0];
    const float* W_up   = (const float*)d_in[1];
    const float* b_up   = (const float*)d_in[2];
    const float* Wh     = (const float*)d_in[3];
    const float* bh     = (const float*)d_in[4];
    const float* Wl     = (const float*)d_in[5];
    const float* bl     = (const float*)d_in[6];
    const float* Wg     = (const float*)d_in[7];
    const float* bg     = (const float*)d_in[8];
    const float* Wf1    = (const float*)d_in[9];
    const float* bf1    = (const float*)d_in[10];
    const float* Wf2    = (const float*)d_in[11];
    const float* bf2v   = (const float*)d_in[12];
    const float* W_down = (const float*)d_in[13];
    const float* b_down = (const float*)d_in[14];

    const int B = in_sizes[0] / 32768;
    float* out = (float*)d_out;

    char* wsp = (char*)d_ws;
    auto alloc = [&](size_t bytes) -> char* {
        char* r = wsp; wsp += (bytes + 255) & ~(size_t)255; return r;
    };

    // ---- fixed: bf16 transposed weights + p_bf ----
    u16* WupT  = (u16*)alloc((size_t)512 * 512 * 2);
    u16* WhT   = (u16*)alloc((size_t)256 * 1024 * 2);
    u16* WlT   = (u16*)alloc((size_t)256 * 1024 * 2);
    u16* WgT   = (u16*)alloc((size_t)1024 * 1024 * 2);
    u16* Wf1T  = (u16*)alloc((size_t)512 * 1024 * 2);
    u16* Wf2T  = (u16*)alloc((size_t)256 * 512 * 2);
    u16* WdT   = (u16*)alloc((size_t)512 * 1024 * 2);
    u16* pbf   = (u16*)alloc((size_t)B * 32768 * 2);

    const size_t fixed_used = (size_t)(wsp - (char*)d_ws);
    // per-batch: upout,g,gT,x (bf16); h,l,attn,p1bf,pd (bf16); logits,p1f,pdf (fp32)
    const size_t perB = ((size_t)131072 + 262144 * 3 + 65536 * 4 + 32768) * 2
                      + ((size_t)65536 * 2 + 32768) * 4;   // 3,080,192 B
    int BC = B;
    while (BC > 1 && fixed_used + (size_t)BC * perB > ws_size) BC >>= 1;

    u16* upout = (u16*)alloc((size_t)BC * 131072 * 2);
    u16* gb    = (u16*)alloc((size_t)BC * 262144 * 2);
    u16* gT    = (u16*)alloc((size_t)BC * 262144 * 2);
    u16* xb    = (u16*)alloc((size_t)BC * 262144 * 2);
    u16* hb    = (u16*)alloc((size_t)BC * 65536 * 2);
    u16* lb    = (u16*)alloc((size_t)BC * 65536 * 2);
    u16* atb   = (u16*)alloc((size_t)BC * 65536 * 2);
    u16* p1bf  = (u16*)alloc((size_t)BC * 65536 * 2);
    u16* pdbf  = (u16*)alloc((size_t)BC * 32768 * 2);
    float* lgt = (float*)alloc((size_t)BC * 65536 * 4);
    float* p1f = (float*)alloc((size_t)BC * 65536 * 4);
    float* pdf = (float*)alloc((size_t)BC * 32768 * 4);

    const dim3 tb(64, 4);
    // ---- startup: convert + transpose (once) ----
    {
        int n4 = B * 8192;
        int nb = (n4 + 255) / 256; if (nb > 2048) nb = 2048;
        cvt_k<<<dim3(nb), dim3(256), 0, stream>>>(p, pbf, n4);
        transpose_k<true><<<dim3(8, 8, 1),  tb, 0, stream>>>(W_up,   WupT, 512, 512);
        transpose_k<true><<<dim3(4, 16, 1), tb, 0, stream>>>(Wh,     WhT, 1024, 256);
        transpose_k<true><<<dim3(4, 16, 1), tb, 0, stream>>>(Wl,     WlT, 1024, 256);
        transpose_k<true><<<dim3(16, 16, 1),tb, 0, stream>>>(Wg,     WgT, 1024, 1024);
        transpose_k<true><<<dim3(8, 16, 1), tb, 0, stream>>>(Wf1,    Wf1T, 1024, 512);
        transpose_k<true><<<dim3(4, 8, 1),  tb, 0, stream>>>(Wf2,    Wf2T, 512, 256);
        transpose_k<true><<<dim3(8, 16, 1), tb, 0, stream>>>(W_down, WdT, 1024, 512);
    }

    const dim3 blk(256);
    auto run_up = [&](const u16* pin_bf, const float* pin_f32,
                      float* f2outF, u16* f2outB, const float* f2EXf, int bc) {
        mgemm<0><<<dim3(4, 2, bc), blk, 0, stream>>>(pin_bf, nullptr, WupT, b_up, nullptr, W_up,
                                                     nullptr, upout, nullptr, 256, 512, 512, 0);
        mgemm<1><<<dim3(2, 2, bc), blk, 0, stream>>>(pin_bf, upout, WhT, bh, nullptr, nullptr,
                                                     nullptr, hb, nullptr, 256, 256, 1024, 0);
        mgemm<1><<<dim3(2, 2, bc), blk, 0, stream>>>(pin_bf, upout, WlT, bl, nullptr, nullptr,
                                                     nullptr, lb, nullptr, 256, 256, 1024, 0);
        mgemm<1><<<dim3(8, 2, bc), blk, 0, stream>>>(pin_bf, upout, WgT, bg, nullptr, nullptr,
                                                     nullptr, gb, nullptr, 256, 1024, 1024, 0);
        mgemm<2><<<dim3(2, 2, bc), blk, 0, stream>>>(lb, nullptr, hb, nullptr, nullptr, nullptr,
                                                     lgt, nullptr, nullptr, 256, 256, 256, 65536);
        softmax_k<<<dim3(bc * 256), dim3(64), 0, stream>>>(lgt, atb);
        transpose_k<false><<<dim3(16, 4, bc), tb, 0, stream>>>(gb, gT, 256, 1024);
        mgemm<3><<<dim3(8, 2, bc), blk, 0, stream>>>(atb, nullptr, gT, nullptr, upout, pin_f32,
                                                     nullptr, xb, nullptr, 256, 1024, 256, 262144);
        mgemm<4><<<dim3(4, 2, bc), blk, 0, stream>>>(xb, nullptr, Wf1T, bf1, nullptr, nullptr,
                                                     nullptr, upout, nullptr, 256, 512, 1024, 0);
        mgemm<5><<<dim3(2, 2, bc), blk, 0, stream>>>(upout, nullptr, Wf2T, bf2v, nullptr, f2EXf,
                                                     f2outF, f2outB, nullptr, 256, 256, 512, 0);
    };

    for (int b0 = 0; b0 < B; b0 += BC) {
        const int bc = (B - b0 < BC) ? (B - b0) : BC;
        const u16*   pin_bf  = pbf + (size_t)b0 * 32768;
        const float* pin_f32 = p   + (size_t)b0 * 32768;
        // up #1 -> p1 (fp32 + bf16)
        run_up(pin_bf, pin_f32, p1f, p1bf, nullptr, bc);
        // pdelta = p - relu(reshape(p1) @ W_down + b)  (fp32 + bf16)
        mgemm<6><<<dim3(4, 1, bc), blk, 0, stream>>>(p1bf, nullptr, WdT, b_down, nullptr, pin_f32,
                                                     nullptr, pdbf, pdf, 64, 512, 1024, 0);
        // up #2 -> d_out chunk, fused "+ p1"
        run_up(pdbf, pdf, out + (size_t)b0 * 65536, nullptr, p1f, bc);
    }
}

// Round 3
// 1023.285 us; speedup vs baseline: 7.4141x; 1.1606x over previous
//
#include <hip/hip_runtime.h>
#include <cstdint>
#include <cstddef>

// FoldingBlock round 3: bf16 MFMA + counted-vmcnt double-buffered pipeline.
// p1 = up(p); pdelta = p - down(p1); out = p1 + up(pdelta)
// Changes vs round 2:
//  - GEMM core: depth-2 prefetch, raw s_barrier + s_waitcnt vmcnt(N) (never 0
//    in steady state), LDS XOR-swizzle (16B-unit involution) staged via
//    pre-swizzled global source, s_setprio around MFMA cluster.
//  - h/l/g fused into one N=1536 GEMM (concatenated W^T + bias).
//  - Two geometries: BIG 256x256xBK32 (8 waves) for hlg/x;
//    SMALL 128x128xBK64 (4 waves, 2 blocks/CU) for up/mm/f1/f2/down.

typedef unsigned short u16;
typedef __bf16 bf16x8 __attribute__((ext_vector_type(8)));
typedef float f32x4 __attribute__((ext_vector_type(4)));

__device__ __forceinline__ u16 f2bf(float f) {
    unsigned u = __builtin_bit_cast(unsigned, f);
    unsigned r = (u + 0x7fffu + ((u >> 16) & 1u)) >> 16;
    return (u16)r;
}
__device__ __forceinline__ float bf2f(u16 h) {
    unsigned u = ((unsigned)h) << 16;
    return __builtin_bit_cast(float, u);
}
__device__ __forceinline__ bf16x8 ldfrag(const u16* p) {
    return __builtin_bit_cast(bf16x8, *reinterpret_cast<const uint4*>(p));
}
__device__ __forceinline__ void gload16(const u16* g, u16* l) {
    __builtin_amdgcn_global_load_lds((__attribute__((address_space(1))) void*)g,
                                     (__attribute__((address_space(3))) void*)l,
                                     16, 0, 0);
}

// Modes:
// 0 UP  (SMALL): A=p_bf tiled(&63) K=512, B=WupT; epi pts-rank2(fp32 W_up)+bias+relu -> outB=upout
// 1 HLG (BIG):   A=cat(p_bf,upout) K=1024, B=WhlgT[1536][1024]; epi bias+relu -> outB=h,out1=l,out2=g
// 2 MM  (SMALL): A=l, B=h per-batch (sB) K=256; raw -> outF=logits
// 3 X   (BIG):   A=attn_bf K=256, B=gT per-batch (sB); epi += cat(EXf fp32, A1 bf16) -> outB=x
// 4 F1  (SMALL): A=x K=1024, B=Wf1T; epi bias+relu -> outB=f1out
// 5 F2  (SMALL): A=f1out K=512, B=Wf2T; epi bias+relu (+EXf) -> outF fp32 (+outB bf16 opt)
// 6 DOWN(SMALL): A=reshape(p1_bf)[64][1024], B=WdT; epi EXf - relu(.+bias) -> outF=pdf, outB=pdbf
template<bool BIG, int MODE>
__global__ __launch_bounds__(BIG ? 512 : 256, 2)
void mg(const u16* __restrict__ A0, const u16* __restrict__ A1,
        const u16* __restrict__ Bt, const float* __restrict__ bias,
        const float* __restrict__ EXf,
        float* __restrict__ outF, u16* __restrict__ outB,
        u16* __restrict__ out1, u16* __restrict__ out2,
        int K, long sB)
{
    constexpr int BM = BIG ? 256 : 128;
    constexpr int BN = BIG ? 256 : 128;
    constexpr int BK = BIG ? 32 : 64;
    constexpr int THREADS = BIG ? 512 : 256;
    constexpr int WN = BIG ? 4 : 2;           // waves along N
    constexpr int MI = BIG ? 8 : 4;           // 16-row frags per wave
    constexpr int NJ = 4;                     // 16-col frags per wave
    constexpr int KS = BK / 32;
    constexpr int UPR = BK / 8;               // 16B units per LDS row
    constexpr int UMASK = UPR - 1;
    constexpr int USH = BIG ? 2 : 3;
    constexpr int RA = (BM * UPR) / THREADS;  // stage rounds for A (2 or 4)
    constexpr int RB = (BN * UPR) / THREADS;  // stage rounds for B (2 or 4)

    __shared__ __align__(16) u16 As[2][BM * BK];
    __shared__ __align__(16) u16 Bs[2][BN * BK];

    const int b    = blockIdx.z;
    const int tid  = threadIdx.x;
    const int lane = tid & 63;
    const int w    = tid >> 6;
    const int wr   = w / WN, wc = w % WN;
    const int wrow0 = wr * (BM / (THREADS / 64 / WN));   // BIG: wr*128 ; SMALL: wr*64
    const int wcol0 = wc * (BN / WN);                     // BIG: wc*64  ; SMALL: wc*64
    const int gm0  = blockIdx.y * BM;
    const int gn0  = blockIdx.x * BN;
    const int lm   = lane & 15, hk = lane >> 4;

    const int NT = K / BK;

    auto stage = [&](int kt, int buf) {
        const int kb = kt * BK;
        #pragma unroll
        for (int t = 0; t < RA; ++t) {
            const int idx = tid + t * THREADS;
            const int row = idx >> USH, u = idx & UMASK;
            const int kk = kb + ((u ^ (row & UMASK)) << 3);
            const u16* ga;
            if constexpr (MODE == 0) {
                ga = A0 + ((size_t)b << 15) + (size_t)((gm0 + row) & 63) * 512 + kk;
            } else if constexpr (MODE == 1) {
                const int gr = gm0 + row;
                ga = (kk < 512) ? A0 + ((size_t)b << 15) + (size_t)(gr & 63) * 512 + kk
                                : A1 + ((size_t)b << 17) + (size_t)gr * 512 + (kk - 512);
            } else if constexpr (MODE == 2 || MODE == 3) {
                ga = A0 + ((size_t)b << 16) + (size_t)(gm0 + row) * 256 + kk;
            } else if constexpr (MODE == 4) {
                ga = A0 + ((size_t)b << 18) + (size_t)(gm0 + row) * 1024 + kk;
            } else if constexpr (MODE == 5) {
                ga = A0 + ((size_t)b << 17) + (size_t)(gm0 + row) * 512 + kk;
            } else { // 6
                int gr = gm0 + row; if (gr > 63) gr = 63;
                ga = A0 + ((size_t)b << 16) + (size_t)(gr * 4 + (kk >> 8)) * 256 + (kk & 255);
            }
            gload16(ga, &As[buf][(size_t)(w * 64 + t * THREADS) * 8]);
        }
        #pragma unroll
        for (int t = 0; t < RB; ++t) {
            const int idx = tid + t * THREADS;
            const int row = idx >> USH, u = idx & UMASK;
            const int kk = kb + ((u ^ (row & UMASK)) << 3);
            gload16(Bt + (size_t)b * sB + (size_t)(gn0 + row) * K + kk,
                    &Bs[buf][(size_t)(w * 64 + t * THREADS) * 8]);
        }
    };

    f32x4 acc[MI][NJ];
    #pragma unroll
    for (int i = 0; i < MI; ++i)
        #pragma unroll
        for (int j = 0; j < NJ; ++j)
            acc[i][j] = (f32x4){0.f, 0.f, 0.f, 0.f};

    stage(0, 0);
    stage(1, 1);

    for (int kt = 0; kt < NT; ++kt) {
        const int cur = kt & 1;
        if (kt == NT - 1) {
            asm volatile("s_waitcnt vmcnt(0)" ::: "memory");
        } else if constexpr (RA + RB == 4) {
            asm volatile("s_waitcnt vmcnt(4)" ::: "memory");
        } else {
            asm volatile("s_waitcnt vmcnt(8)" ::: "memory");
        }
        __builtin_amdgcn_s_barrier();
        asm volatile("" ::: "memory");

        #pragma unroll
        for (int ks = 0; ks < KS; ++ks) {
            bf16x8 af[MI], bfr[NJ];
            #pragma unroll
            for (int i = 0; i < MI; ++i) {
                const int row = wrow0 + i * 16 + lm;
                af[i] = ldfrag(&As[cur][(size_t)row * BK + (((ks * 4 + hk) ^ (row & UMASK)) << 3)]);
            }
            #pragma unroll
            for (int j = 0; j < NJ; ++j) {
                const int row = wcol0 + j * 16 + lm;
                bfr[j] = ldfrag(&Bs[cur][(size_t)row * BK + (((ks * 4 + hk) ^ (row & UMASK)) << 3)]);
            }
            __builtin_amdgcn_s_setprio(1);
            #pragma unroll
            for (int i = 0; i < MI; ++i)
                #pragma unroll
                for (int j = 0; j < NJ; ++j)
                    acc[i][j] = __builtin_amdgcn_mfma_f32_16x16x32_bf16(af[i], bfr[j], acc[i][j], 0, 0, 0);
            __builtin_amdgcn_s_setprio(0);
        }

        asm volatile("" ::: "memory");
        __builtin_amdgcn_s_barrier();
        if (kt + 2 < NT) stage(kt + 2, cur);
    }

    // ---- epilogue ----
    #pragma unroll
    for (int i = 0; i < MI; ++i) {
        #pragma unroll
        for (int r = 0; r < 4; ++r) {
            const int row = gm0 + wrow0 + i * 16 + hk * 4 + r;
            if (MODE == 6 && row >= 64) continue;
            #pragma unroll
            for (int j = 0; j < NJ; ++j) {
                const int col = gn0 + wcol0 + j * 16 + lm;
                float v = acc[i][j][r];
                if constexpr (MODE == 0) {
                    const float px = -0.3f + 0.04f * (float)(row >> 4);
                    const float py = -0.3f + 0.04f * (float)(row & 15);
                    v += px * EXf[(size_t)512 * 512 + col] + py * EXf[(size_t)513 * 512 + col];
                    v = fmaxf(v + bias[col], 0.0f);
                    outB[((size_t)b << 17) + (size_t)row * 512 + col] = f2bf(v);
                } else if constexpr (MODE == 1) {
                    v = fmaxf(v + bias[col], 0.0f);
                    if (col < 256)      outB[((size_t)b << 16) + (size_t)row * 256 + col] = f2bf(v);
                    else if (col < 512) out1[((size_t)b << 16) + (size_t)row * 256 + (col - 256)] = f2bf(v);
                    else                out2[((size_t)b << 18) + (size_t)row * 1024 + (col - 512)] = f2bf(v);
                } else if constexpr (MODE == 2) {
                    outF[((size_t)b << 16) + (size_t)row * 256 + col] = v;
                } else if constexpr (MODE == 3) {
                    float cv = (col < 512)
                        ? EXf[((size_t)b << 15) + (size_t)(row & 63) * 512 + col]
                        : bf2f(A1[((size_t)b << 17) + (size_t)row * 512 + (col - 512)]);
                    v += cv;
                    outB[((size_t)b << 18) + (size_t)row * 1024 + col] = f2bf(v);
                } else if constexpr (MODE == 4) {
                    v = fmaxf(v + bias[col], 0.0f);
                    outB[((size_t)b << 17) + (size_t)row * 512 + col] = f2bf(v);
                } else if constexpr (MODE == 5) {
                    v = fmaxf(v + bias[col], 0.0f);
                    const size_t oidx = ((size_t)b << 16) + (size_t)row * 256 + col;
                    if (EXf) v += EXf[oidx];
                    outF[oidx] = v;
                    if (outB) outB[oidx] = f2bf(v);
                } else if constexpr (MODE == 6) {
                    v = fmaxf(v + bias[col], 0.0f);
                    const size_t oidx = ((size_t)b << 15) + (size_t)row * 512 + col;
                    v = EXf[oidx] - v;
                    outF[oidx] = v;
                    outB[oidx] = f2bf(v);
                }
            }
        }
    }
}

// Transpose + convert: in [R][C] fp32/bf16 -> out [C][R] bf16. R,C multiples of 64.
template<bool F32IN>
__global__ __launch_bounds__(256)
void transpose_k(const void* __restrict__ in_, u16* __restrict__ out, int R, int C)
{
    __shared__ float t[64][65];
    const size_t zo = (size_t)blockIdx.z * (size_t)R * C;
    const int c0 = blockIdx.x * 64, r0 = blockIdx.y * 64;
    const int x = threadIdx.x, y = threadIdx.y;
    #pragma unroll
    for (int i = 0; i < 16; ++i) {
        const int r = y * 16 + i;
        float v;
        if constexpr (F32IN) v = ((const float*)in_)[zo + (size_t)(r0 + r) * C + c0 + x];
        else                 v = bf2f(((const u16*)in_)[zo + (size_t)(r0 + r) * C + c0 + x]);
        t[r][x] = v;
    }
    __syncthreads();
    #pragma unroll
    for (int i = 0; i < 16; ++i) {
        const int c = y * 16 + i;
        out[zo + (size_t)(c0 + c) * R + r0 + x] = f2bf(t[x][c]);
    }
}

__global__ __launch_bounds__(256)
void cvt_k(const float* __restrict__ in, u16* __restrict__ out, int n4)
{
    int i = blockIdx.x * 256 + threadIdx.x;
    const int stride = gridDim.x * 256;
    for (; i < n4; i += stride) {
        float4 v = ((const float4*)in)[i];
        ushort4 o;
        o.x = f2bf(v.x); o.y = f2bf(v.y); o.z = f2bf(v.z); o.w = f2bf(v.w);
        ((ushort4*)out)[i] = o;
    }
}

__global__ __launch_bounds__(512)
void concat3_k(const float* __restrict__ a, const float* __restrict__ bb,
               const float* __restrict__ c, float* __restrict__ o)
{
    const int i = blockIdx.x * 512 + threadIdx.x;
    if (i < 256)       o[i] = a[i];
    else if (i < 512)  o[i] = bb[i - 256];
    else if (i < 1536) o[i] = c[i - 512];
}

// One wave per 256-float row: softmax fp32 -> bf16
__global__ __launch_bounds__(64)
void softmax_k(const float* __restrict__ logits, u16* __restrict__ attn)
{
    const size_t row = blockIdx.x;
    const float4 v = ((const float4*)(logits + row * 256))[threadIdx.x];
    float mx = fmaxf(fmaxf(v.x, v.y), fmaxf(v.z, v.w));
    #pragma unroll
    for (int o = 32; o > 0; o >>= 1) mx = fmaxf(mx, __shfl_xor(mx, o));
    float e0 = expf(v.x - mx), e1 = expf(v.y - mx), e2 = expf(v.z - mx), e3 = expf(v.w - mx);
    float s = e0 + e1 + e2 + e3;
    #pragma unroll
    for (int o = 32; o > 0; o >>= 1) s += __shfl_xor(s, o);
    const float inv = 1.0f / s;
    ushort4 o;
    o.x = f2bf(e0 * inv); o.y = f2bf(e1 * inv); o.z = f2bf(e2 * inv); o.w = f2bf(e3 * inv);
    ((ushort4*)(attn + row * 256))[threadIdx.x] = o;
}

extern "C" void kernel_launch(void* const* d_in, const int* in_sizes, int n_in,
                              void* d_out, int out_size, void* d_ws, size_t ws_size,
                              hipStream_t stream)
{
    const float* p      = (const float*)d_in[0];
    const float* W_up   = (const float*)d_in[1];
    const float* b_up   = (const float*)d_in[2];
    const float* Wh     = (const float*)d_in[3];
    const float* bh     = (const float*)d_in[4];
    const float* Wl     = (const float*)d_in[5];
    const float* bl     = (const float*)d_in[6];
    const float* Wg     = (const float*)d_in[7];
    const float* bg     = (const float*)d_in[8];
    const float* Wf1    = (const float*)d_in[9];
    const float* bf1    = (const float*)d_in[10];
    const float* Wf2    = (const float*)d_in[11];
    const float* bf2v   = (const float*)d_in[12];
    const float* W_down = (const float*)d_in[13];
    const float* b_down = (const float*)d_in[14];

    const int B = in_sizes[0] / 32768;
    float* out = (float*)d_out;

    char* wsp = (char*)d_ws;
    auto alloc = [&](size_t bytes) -> char* {
        char* r = wsp; wsp += (bytes + 255) & ~(size_t)255; return r;
    };

    // ---- fixed buffers ----
    u16* WupT  = (u16*)alloc((size_t)512 * 512 * 2);
    u16* WhlgT = (u16*)alloc((size_t)1536 * 1024 * 2);
    u16* Wf1T  = (u16*)alloc((size_t)512 * 1024 * 2);
    u16* Wf2T  = (u16*)alloc((size_t)256 * 512 * 2);
    u16* WdT   = (u16*)alloc((size_t)512 * 1024 * 2);
    float* bias_hlg = (float*)alloc((size_t)1536 * 4);
    u16* pbf   = (u16*)alloc((size_t)B * 32768 * 2);

    const size_t fixed_used = (size_t)(wsp - (char*)d_ws);
    const size_t perB = 2555904;   // bytes (see buffer list below)
    int BC = B;
    while (BC > 1 && fixed_used + (size_t)BC * perB > ws_size) BC >>= 1;

    u16* upout = (u16*)alloc((size_t)BC * 131072 * 2);
    u16* gb    = (u16*)alloc((size_t)BC * 262144 * 2);
    u16* gT    = (u16*)alloc((size_t)BC * 262144 * 2);
    u16* xb    = gb;   // g dead after transpose; x aliases g
    u16* hb    = (u16*)alloc((size_t)BC * 65536 * 2);
    u16* lb    = (u16*)alloc((size_t)BC * 65536 * 2);
    u16* atb   = (u16*)alloc((size_t)BC * 65536 * 2);
    u16* p1bf  = (u16*)alloc((size_t)BC * 65536 * 2);
    u16* pdbf  = (u16*)alloc((size_t)BC * 32768 * 2);
    float* lgt = (float*)alloc((size_t)BC * 65536 * 4);
    float* p1f = (float*)alloc((size_t)BC * 65536 * 4);
    float* pdf = (float*)alloc((size_t)BC * 32768 * 4);

    const dim3 tb(64, 4);
    // ---- startup: convert + transpose + concat (once) ----
    {
        int n4 = B * 8192;
        int nb = (n4 + 255) / 256; if (nb > 2048) nb = 2048;
        cvt_k<<<dim3(nb), dim3(256), 0, stream>>>(p, pbf, n4);
        transpose_k<true><<<dim3(8, 8, 1),  tb, 0, stream>>>(W_up, WupT, 512, 512);
        transpose_k<true><<<dim3(4, 16, 1), tb, 0, stream>>>(Wh, WhlgT, 1024, 256);
        transpose_k<true><<<dim3(4, 16, 1), tb, 0, stream>>>(Wl, WhlgT + (size_t)256 * 1024, 1024, 256);
        transpose_k<true><<<dim3(16, 16, 1),tb, 0, stream>>>(Wg, WhlgT + (size_t)512 * 1024, 1024, 1024);
        transpose_k<true><<<dim3(8, 16, 1), tb, 0, stream>>>(Wf1, Wf1T, 1024, 512);
        transpose_k<true><<<dim3(4, 8, 1),  tb, 0, stream>>>(Wf2, Wf2T, 512, 256);
        transpose_k<true><<<dim3(8, 16, 1), tb, 0, stream>>>(W_down, WdT, 1024, 512);
        concat3_k<<<dim3(3), dim3(512), 0, stream>>>(bh, bl, bg, bias_hlg);
    }

    auto run_up = [&](const u16* pin_bf, const float* pin_f32,
                      float* f2outF, u16* f2outB, const float* f2EXf, int bc) {
        mg<false,0><<<dim3(4, 2, bc), dim3(256), 0, stream>>>(
            pin_bf, nullptr, WupT, b_up, W_up, nullptr, upout, nullptr, nullptr, 512, 0);
        mg<true,1><<<dim3(6, 1, bc), dim3(512), 0, stream>>>(
            pin_bf, upout, WhlgT, bias_hlg, nullptr, nullptr, hb, lb, gb, 1024, 0);
        mg<false,2><<<dim3(2, 2, bc), dim3(256), 0, stream>>>(
            lb, nullptr, hb, nullptr, nullptr, lgt, nullptr, nullptr, nullptr, 256, 65536);
        softmax_k<<<dim3(bc * 256), dim3(64), 0, stream>>>(lgt, atb);
        transpose_k<false><<<dim3(16, 4, bc), tb, 0, stream>>>(gb, gT, 256, 1024);
        mg<true,3><<<dim3(4, 1, bc), dim3(512), 0, stream>>>(
            atb, upout, gT, nullptr, pin_f32, nullptr, xb, nullptr, nullptr, 256, 262144);
        mg<false,4><<<dim3(4, 2, bc), dim3(256), 0, stream>>>(
            xb, nullptr, Wf1T, bf1, nullptr, nullptr, upout, nullptr, nullptr, 1024, 0);
        mg<false,5><<<dim3(2, 2, bc), dim3(256), 0, stream>>>(
            upout, nullptr, Wf2T, bf2v, f2EXf, f2outF, f2outB, nullptr, nullptr, 512, 0);
    };

    for (int b0 = 0; b0 < B; b0 += BC) {
        const int bc = (B - b0 < BC) ? (B - b0) : BC;
        const u16*   pin_bf  = pbf + (size_t)b0 * 32768;
        const float* pin_f32 = p   + (size_t)b0 * 32768;
        // up #1 -> p1 (fp32 + bf16)
        run_up(pin_bf, pin_f32, p1f, p1bf, nullptr, bc);
        // pdelta = p - relu(reshape(p1) @ W_down + b)
        mg<false,6><<<dim3(4, 1, bc), dim3(256), 0, stream>>>(
            p1bf, nullptr, WdT, b_down, pin_f32, pdf, pdbf, nullptr, nullptr, 1024, 0);
        // up #2 -> d_out chunk, fused "+ p1"
        run_up(pdbf, pdf, out + (size_t)b0 * 65536, nullptr, p1f, bc);
    }
}